// Round 1
// baseline (1370.229 us; speedup 1.0000x reference)
//
#include <hip/hip_runtime.h>
#include <math.h>

// GCN 2-layer, N=100000 nodes, E=6400000 edges, Fin=1, Fhid=16, Fout=2.
// Key reduction: Fin==1 means layer-1 aggregation is a scalar scatter;
// layer-2 aggregation is a 2-float scatter. Node arrays (<=800KB) stay in L2.

__global__ void k_deg(const int* __restrict__ dst, float* __restrict__ deg, int E) {
    int i = blockIdx.x * blockDim.x + threadIdx.x;
    if (i < E) atomicAdd(&deg[dst[i]], 1.0f);
}

__global__ void k_dinv_y(const float* __restrict__ x, float* __restrict__ deg_dinv,
                         float* __restrict__ y, int N) {
    int i = blockIdx.x * blockDim.x + threadIdx.x;
    if (i < N) {
        float d = deg_dinv[i] + 1.0f;   // +1 self-loop
        float dinv = rsqrtf(d);         // d >= 1 always, no zero case
        deg_dinv[i] = dinv;
        y[i] = dinv * x[i];
    }
}

__global__ void k_scatter1(const int* __restrict__ src, const int* __restrict__ dst,
                           const float* __restrict__ y, float* __restrict__ Sacc, int E) {
    int i = blockIdx.x * blockDim.x + threadIdx.x;
    if (i < E) atomicAdd(&Sacc[dst[i]], y[src[i]]);
}

__global__ void k_layer(const float* __restrict__ dinv, const float* __restrict__ y,
                        const float* __restrict__ Sacc,
                        const float* __restrict__ W1, const float* __restrict__ b1,
                        const float* __restrict__ W2,
                        float* __restrict__ gy, int N) {
    int i = blockIdx.x * blockDim.x + threadIdx.x;
    if (i >= N) return;
    float di = dinv[i];
    float S = di * (Sacc[i] + y[i]);    // self-loop contributes y[i]
    float g0 = 0.f, g1 = 0.f;
#pragma unroll
    for (int f = 0; f < 16; f++) {
        float h = fmaxf(fmaf(W1[f], S, b1[f]), 0.0f);  // relu(x@W1 + b1)
        g0 = fmaf(h, W2[2 * f], g0);                   // @ W2 (row-major [16,2])
        g1 = fmaf(h, W2[2 * f + 1], g1);
    }
    gy[2 * i]     = di * g0;   // pre-multiplied by dinv[src]
    gy[2 * i + 1] = di * g1;
}

__global__ void k_scatter2(const int* __restrict__ src, const int* __restrict__ dst,
                           const float* __restrict__ gy, float* __restrict__ T, int E) {
    int i = blockIdx.x * blockDim.x + threadIdx.x;
    if (i < E) {
        int s = src[i], d = dst[i];
        float2 v = ((const float2*)gy)[s];
        atomicAdd(&T[2 * d], v.x);
        atomicAdd(&T[2 * d + 1], v.y);
    }
}

__global__ void k_out(const float* __restrict__ dinv, const float* __restrict__ gy,
                      const float* __restrict__ T, const float* __restrict__ b2,
                      float* __restrict__ out, int N) {
    int i = blockIdx.x * blockDim.x + threadIdx.x;
    if (i >= N) return;
    float di = dinv[i];
    float z0 = di * (T[2 * i] + gy[2 * i]) + b2[0];         // self-loop: gy[i]
    float z1 = di * (T[2 * i + 1] + gy[2 * i + 1]) + b2[1];
    float m = fmaxf(z0, z1);
    float l = logf(expf(z0 - m) + expf(z1 - m));
    out[2 * i]     = z0 - m - l;
    out[2 * i + 1] = z1 - m - l;
}

extern "C" void kernel_launch(void* const* d_in, const int* in_sizes, int n_in,
                              void* d_out, int out_size, void* d_ws, size_t ws_size,
                              hipStream_t stream) {
    const float* x   = (const float*)d_in[0];
    const int* ei    = (const int*)d_in[1];
    const float* W1  = (const float*)d_in[2];
    const float* b1  = (const float*)d_in[3];
    const float* W2  = (const float*)d_in[4];
    const float* b2  = (const float*)d_in[5];
    float* out = (float*)d_out;

    const int N = in_sizes[0];       // 100000 (x is [N,1])
    const int E = in_sizes[1] / 2;   // 6400000
    const int* src = ei;             // edge_index[0]
    const int* dst = ei + E;         // edge_index[1]

    // workspace layout (floats): deg/dinv[N] | Sacc[N] | T[2N] | y[N] | gy[2N]
    float* ws   = (float*)d_ws;
    float* dinv = ws;
    float* Sacc = ws + (size_t)N;
    float* T    = ws + (size_t)2 * N;
    float* y    = ws + (size_t)4 * N;
    float* gy   = ws + (size_t)5 * N;

    // zero accumulators (deg, Sacc, T are the first 4N floats)
    hipMemsetAsync(d_ws, 0, (size_t)4 * N * sizeof(float), stream);

    const int BT = 256;
    const int gE = (E + BT - 1) / BT;
    const int gN = (N + BT - 1) / BT;

    k_deg<<<gE, BT, 0, stream>>>(dst, dinv, E);
    k_dinv_y<<<gN, BT, 0, stream>>>(x, dinv, y, N);
    k_scatter1<<<gE, BT, 0, stream>>>(src, dst, y, Sacc, E);
    k_layer<<<gN, BT, 0, stream>>>(dinv, y, Sacc, W1, b1, W2, gy, N);
    k_scatter2<<<gE, BT, 0, stream>>>(src, dst, gy, T, E);
    k_out<<<gN, BT, 0, stream>>>(dinv, gy, T, b2, out, N);
}

// Round 2
// 353.201 us; speedup vs baseline: 3.8795x; 3.8795x over previous
//
#include <hip/hip_runtime.h>
#include <math.h>

// GCN 2-layer, N=100000, E=6400000, Fin=1, Fhid=16, Fout=2.
// R2 strategy: NO global atomics. Counting-sort edges into coarse buckets of
// 128 dst-nodes (782 buckets) via per-block LDS histograms + 3-phase scan.
// Then deg / layer1-sum / layer2-sum are LDS-atomic segmented reductions
// (128-node accumulator per block fits trivially in LDS).
// Edge payload packed as (dst&127)<<20 | src  (src < 2^17 < 2^20).

#define BKT_SHIFT 7
#define BKT_MASK 127
#define B1 1024        // blocks for hist/place (chunked edge passes)
#define SCAN_T 512

__global__ void k_hist(const int* __restrict__ dst, int* __restrict__ G,
                       int E, int chunk, int nbkt) {
    extern __shared__ int sh[]; // nbkt ints
    int blk = blockIdx.x;
    for (int j = threadIdx.x; j < nbkt; j += blockDim.x) sh[j] = 0;
    __syncthreads();
    int s0 = blk * chunk, s1 = min(E, s0 + chunk);
    for (int i = s0 + threadIdx.x; i < s1; i += blockDim.x)
        atomicAdd(&sh[dst[i] >> BKT_SHIFT], 1);
    __syncthreads();
    for (int j = threadIdx.x; j < nbkt; j += blockDim.x)
        G[(size_t)j * gridDim.x + blk] = sh[j];   // bucket-major for the scan
}

// exclusive scan, phase 1: per-block scan + block totals
__global__ void k_scan1(int* __restrict__ G, int* __restrict__ part, int NG) {
    __shared__ int sh[SCAN_T];
    int t = threadIdx.x;
    int i = blockIdx.x * SCAN_T + t;
    int v = (i < NG) ? G[i] : 0;
    sh[t] = v;
    __syncthreads();
    for (int off = 1; off < SCAN_T; off <<= 1) {
        int u = (t >= off) ? sh[t - off] : 0;
        __syncthreads();
        sh[t] += u;
        __syncthreads();
    }
    if (i < NG) G[i] = sh[t] - v;                    // exclusive within block
    if (t == SCAN_T - 1) part[blockIdx.x] = sh[t];   // block total
}

// phase 2: single block scans the block totals (exclusive, in place)
__global__ void k_scan2(int* __restrict__ part, int NP) {
    __shared__ int sh[SCAN_T];
    int t = threadIdx.x;
    int carry = 0;
    for (int base = 0; base < NP; base += SCAN_T) {
        int i = base + t;
        int v = (i < NP) ? part[i] : 0;
        sh[t] = v;
        __syncthreads();
        for (int off = 1; off < SCAN_T; off <<= 1) {
            int u = (t >= off) ? sh[t - off] : 0;
            __syncthreads();
            sh[t] += u;
            __syncthreads();
        }
        if (i < NP) part[i] = carry + sh[t] - v;
        carry += sh[SCAN_T - 1];
        __syncthreads();
    }
}

// phase 3: add scanned block offsets
__global__ void k_scan3(int* __restrict__ G, const int* __restrict__ part, int NG) {
    int i = blockIdx.x * SCAN_T + threadIdx.x;
    if (i < NG) G[i] += part[blockIdx.x];
}

__global__ void k_place(const int* __restrict__ src, const int* __restrict__ dst,
                        const int* __restrict__ Gs, int* __restrict__ packed,
                        int E, int chunk, int nbkt) {
    extern __shared__ int base[]; // nbkt ints
    int blk = blockIdx.x;
    for (int j = threadIdx.x; j < nbkt; j += blockDim.x)
        base[j] = Gs[(size_t)j * gridDim.x + blk];
    __syncthreads();
    int s0 = blk * chunk, s1 = min(E, s0 + chunk);
    for (int i = s0 + threadIdx.x; i < s1; i += blockDim.x) {
        int d = dst[i], s = src[i];
        int b = d >> BKT_SHIFT;
        int pos = atomicAdd(&base[b], 1);            // LDS atomic -> unique global slot
        packed[pos] = ((d & BKT_MASK) << 20) | s;
    }
}

// per-bucket degree count -> dinv + y = dinv*x
__global__ void k_dinv_y(const int* __restrict__ packed, const int* __restrict__ Gs,
                         const float* __restrict__ x, float* __restrict__ dinv,
                         float* __restrict__ y, int E, int N, int nbkt) {
    __shared__ int cnt[128];
    int b = blockIdx.x;
    if (threadIdx.x < 128) cnt[threadIdx.x] = 0;
    __syncthreads();
    int s0 = Gs[(size_t)b * B1];
    int s1 = (b + 1 < nbkt) ? Gs[(size_t)(b + 1) * B1] : E;
    for (int i = s0 + threadIdx.x; i < s1; i += blockDim.x)
        atomicAdd(&cnt[packed[i] >> 20], 1);
    __syncthreads();
    int l = threadIdx.x;
    if (l < 128) {
        int node = (b << BKT_SHIFT) + l;
        if (node < N) {
            float di = rsqrtf((float)cnt[l] + 1.0f);  // +1 self-loop, deg>=1
            dinv[node] = di;
            y[node] = di * x[node];
        }
    }
}

// layer-1 aggregation (scalar) + fused 1->16 relu MLP -> 16->2, premul dinv
__global__ void k_agg1(const int* __restrict__ packed, const int* __restrict__ Gs,
                       const float* __restrict__ dinv, const float* __restrict__ y,
                       const float* __restrict__ W1, const float* __restrict__ b1,
                       const float* __restrict__ W2,
                       float* __restrict__ gy, int E, int N, int nbkt) {
    __shared__ float acc[128];
    int b = blockIdx.x;
    if (threadIdx.x < 128) acc[threadIdx.x] = 0.f;
    __syncthreads();
    int s0 = Gs[(size_t)b * B1];
    int s1 = (b + 1 < nbkt) ? Gs[(size_t)(b + 1) * B1] : E;
    for (int i = s0 + threadIdx.x; i < s1; i += blockDim.x) {
        int p = packed[i];
        atomicAdd(&acc[p >> 20], y[p & 0xFFFFF]);
    }
    __syncthreads();
    int l = threadIdx.x;
    if (l < 128) {
        int node = (b << BKT_SHIFT) + l;
        if (node < N) {
            float di = dinv[node];
            float S = di * (acc[l] + y[node]);        // self-loop adds y[node]
            float g0 = 0.f, g1 = 0.f;
#pragma unroll
            for (int f = 0; f < 16; f++) {
                float h = fmaxf(fmaf(W1[f], S, b1[f]), 0.f);
                g0 = fmaf(h, W2[2 * f], g0);
                g1 = fmaf(h, W2[2 * f + 1], g1);
            }
            gy[2 * node]     = di * g0;               // premultiplied by dinv[src]
            gy[2 * node + 1] = di * g1;
        }
    }
}

// layer-2 aggregation (2 floats) + bias + log_softmax
__global__ void k_agg2(const int* __restrict__ packed, const int* __restrict__ Gs,
                       const float* __restrict__ dinv, const float* __restrict__ gy,
                       const float* __restrict__ b2, float* __restrict__ out,
                       int E, int N, int nbkt) {
    __shared__ float acc[256];
    int t = threadIdx.x;
    acc[t] = 0.f;   // blockDim == 256
    __syncthreads();
    int b = blockIdx.x;
    int s0 = Gs[(size_t)b * B1];
    int s1 = (b + 1 < nbkt) ? Gs[(size_t)(b + 1) * B1] : E;
    for (int i = s0 + t; i < s1; i += blockDim.x) {
        int p = packed[i];
        int l = p >> 20, s = p & 0xFFFFF;
        float2 v = ((const float2*)gy)[s];
        atomicAdd(&acc[2 * l],     v.x);
        atomicAdd(&acc[2 * l + 1], v.y);
    }
    __syncthreads();
    if (t < 128) {
        int node = (b << BKT_SHIFT) + t;
        if (node < N) {
            float di = dinv[node];
            float z0 = di * (acc[2 * t]     + gy[2 * node])     + b2[0];
            float z1 = di * (acc[2 * t + 1] + gy[2 * node + 1]) + b2[1];
            float m = fmaxf(z0, z1);
            float lse = logf(expf(z0 - m) + expf(z1 - m));
            out[2 * node]     = z0 - m - lse;
            out[2 * node + 1] = z1 - m - lse;
        }
    }
}

extern "C" void kernel_launch(void* const* d_in, const int* in_sizes, int n_in,
                              void* d_out, int out_size, void* d_ws, size_t ws_size,
                              hipStream_t stream) {
    const float* x  = (const float*)d_in[0];
    const int* ei   = (const int*)d_in[1];
    const float* W1 = (const float*)d_in[2];
    const float* b1 = (const float*)d_in[3];
    const float* W2 = (const float*)d_in[4];
    const float* b2 = (const float*)d_in[5];
    float* out = (float*)d_out;

    const int N = in_sizes[0];       // 100000
    const int E = in_sizes[1] / 2;   // 6400000
    const int* src = ei;
    const int* dst = ei + E;

    const int nbkt  = (N + BKT_MASK) >> BKT_SHIFT;       // 782
    const int chunk = (E + B1 - 1) / B1;                 // 6250
    const int NG    = nbkt * B1;                         // 800768
    const int scanB = (NG + SCAN_T - 1) / SCAN_T;        // 1564
    const int nodesPad = nbkt << BKT_SHIFT;              // 100096

    // ws layout: G[NG] | part[scanB] | packed[E] | dinv[np] | y[np] | gy[2np]
    int* G      = (int*)d_ws;
    int* part   = G + NG;
    int* packed = part + scanB;
    float* dinv = (float*)(packed + E);
    float* y    = dinv + nodesPad;
    float* gy   = y + nodesPad;
    // total ~30.5 MB; every cell fully written before read -> no memset needed

    const int BT = 256;
    const size_t ldsHist = (size_t)nbkt * sizeof(int);

    k_hist <<<B1,    BT,     ldsHist, stream>>>(dst, G, E, chunk, nbkt);
    k_scan1<<<scanB, SCAN_T, 0,       stream>>>(G, part, NG);
    k_scan2<<<1,     SCAN_T, 0,       stream>>>(part, scanB);
    k_scan3<<<scanB, SCAN_T, 0,       stream>>>(G, part, NG);
    k_place<<<B1,    BT,     ldsHist, stream>>>(src, dst, G, packed, E, chunk, nbkt);
    k_dinv_y<<<nbkt, BT,     0,       stream>>>(packed, G, x, dinv, y, E, N, nbkt);
    k_agg1 <<<nbkt,  BT,     0,       stream>>>(packed, G, dinv, y, W1, b1, W2, gy, E, N, nbkt);
    k_agg2 <<<nbkt,  BT,     0,       stream>>>(packed, G, dinv, gy, b2, out, E, N, nbkt);
}

// Round 4
// 305.012 us; speedup vs baseline: 4.4924x; 1.1580x over previous
//
#include <hip/hip_runtime.h>
#include <math.h>

// GCN 2-layer, N=100000, E=6400000, Fin=1, Fhid=16, Fout=2.
// R4 = R2 (known-good: global counting sort into 128-node buckets, LDS-atomic
// segmented aggregation, no global atomics) with ONE perf change:
//   B1 1024 -> 256 so each (bucket,block) write run in k_place is ~32 edges
//   (128 B) instead of ~8 (32 B) -> kills the 6.4x write amplification.
// Plus int4 vectorized edge reads in k_hist/k_place (E/B1=25000, /4 exact).
// R3's block-private-region + 54KB-LDS-staging variant failed a graph-replay
// tripwire for unidentified reasons; avoiding large dynamic-LDS kernels.
// packed word = (dst&127)<<20 | src  (src < 2^17 < 2^20).

#define BKT_SHIFT 7
#define BKT_MASK 127
#define B1 256         // blocks for hist/place (chunked edge passes)
#define SCAN_T 512

__global__ void k_hist(const int* __restrict__ dst, int* __restrict__ G,
                       int E, int chunk, int nbkt) {
    extern __shared__ int sh[]; // nbkt ints
    int blk = blockIdx.x;
    for (int j = threadIdx.x; j < nbkt; j += blockDim.x) sh[j] = 0;
    __syncthreads();
    int s0 = blk * chunk;
    int n4 = chunk >> 2;   // chunk==25000, exact multiple of 4
    const int4* dst4 = (const int4*)(dst + s0);
    for (int i = threadIdx.x; i < n4; i += blockDim.x) {
        int4 d = dst4[i];
        atomicAdd(&sh[d.x >> BKT_SHIFT], 1);
        atomicAdd(&sh[d.y >> BKT_SHIFT], 1);
        atomicAdd(&sh[d.z >> BKT_SHIFT], 1);
        atomicAdd(&sh[d.w >> BKT_SHIFT], 1);
    }
    __syncthreads();
    for (int j = threadIdx.x; j < nbkt; j += blockDim.x)
        G[(size_t)j * gridDim.x + blk] = sh[j];   // bucket-major for the scan
}

// exclusive scan, phase 1: per-block scan + block totals
__global__ void k_scan1(int* __restrict__ G, int* __restrict__ part, int NG) {
    __shared__ int sh[SCAN_T];
    int t = threadIdx.x;
    int i = blockIdx.x * SCAN_T + t;
    int v = (i < NG) ? G[i] : 0;
    sh[t] = v;
    __syncthreads();
    for (int off = 1; off < SCAN_T; off <<= 1) {
        int u = (t >= off) ? sh[t - off] : 0;
        __syncthreads();
        sh[t] += u;
        __syncthreads();
    }
    if (i < NG) G[i] = sh[t] - v;                    // exclusive within block
    if (t == SCAN_T - 1) part[blockIdx.x] = sh[t];   // block total
}

// phase 2: single block scans the block totals (exclusive, in place)
__global__ void k_scan2(int* __restrict__ part, int NP) {
    __shared__ int sh[SCAN_T];
    int t = threadIdx.x;
    int carry = 0;
    for (int base = 0; base < NP; base += SCAN_T) {
        int i = base + t;
        int v = (i < NP) ? part[i] : 0;
        sh[t] = v;
        __syncthreads();
        for (int off = 1; off < SCAN_T; off <<= 1) {
            int u = (t >= off) ? sh[t - off] : 0;
            __syncthreads();
            sh[t] += u;
            __syncthreads();
        }
        if (i < NP) part[i] = carry + sh[t] - v;
        carry += sh[SCAN_T - 1];
        __syncthreads();
    }
}

// phase 3: add scanned block offsets
__global__ void k_scan3(int* __restrict__ G, const int* __restrict__ part, int NG) {
    int i = blockIdx.x * SCAN_T + threadIdx.x;
    if (i < NG) G[i] += part[blockIdx.x];
}

__global__ void k_place(const int* __restrict__ src, const int* __restrict__ dst,
                        const int* __restrict__ Gs, int* __restrict__ packed,
                        int E, int chunk, int nbkt) {
    extern __shared__ int base[]; // nbkt ints
    int blk = blockIdx.x;
    for (int j = threadIdx.x; j < nbkt; j += blockDim.x)
        base[j] = Gs[(size_t)j * gridDim.x + blk];
    __syncthreads();
    int s0 = blk * chunk;
    int n4 = chunk >> 2;
    const int4* dst4 = (const int4*)(dst + s0);
    const int4* src4 = (const int4*)(src + s0);
    for (int i = threadIdx.x; i < n4; i += blockDim.x) {
        int4 d = dst4[i];
        int4 s = src4[i];
        int b, p;
        b = d.x >> BKT_SHIFT; p = atomicAdd(&base[b], 1); packed[p] = ((d.x & BKT_MASK) << 20) | s.x;
        b = d.y >> BKT_SHIFT; p = atomicAdd(&base[b], 1); packed[p] = ((d.y & BKT_MASK) << 20) | s.y;
        b = d.z >> BKT_SHIFT; p = atomicAdd(&base[b], 1); packed[p] = ((d.z & BKT_MASK) << 20) | s.z;
        b = d.w >> BKT_SHIFT; p = atomicAdd(&base[b], 1); packed[p] = ((d.w & BKT_MASK) << 20) | s.w;
    }
}

// per-bucket degree count -> dinv + y = dinv*x
__global__ void k_dinv_y(const int* __restrict__ packed, const int* __restrict__ Gs,
                         const float* __restrict__ x, float* __restrict__ dinv,
                         float* __restrict__ y, int E, int N, int nbkt) {
    __shared__ int cnt[128];
    int b = blockIdx.x;
    if (threadIdx.x < 128) cnt[threadIdx.x] = 0;
    __syncthreads();
    int s0 = Gs[(size_t)b * B1];
    int s1 = (b + 1 < nbkt) ? Gs[(size_t)(b + 1) * B1] : E;
    for (int i = s0 + threadIdx.x; i < s1; i += blockDim.x)
        atomicAdd(&cnt[packed[i] >> 20], 1);
    __syncthreads();
    int l = threadIdx.x;
    if (l < 128) {
        int node = (b << BKT_SHIFT) + l;
        if (node < N) {
            float di = rsqrtf((float)cnt[l] + 1.0f);  // +1 self-loop, deg>=1
            dinv[node] = di;
            y[node] = di * x[node];
        }
    }
}

// layer-1 aggregation (scalar) + fused 1->16 relu MLP -> 16->2, premul dinv
__global__ void k_agg1(const int* __restrict__ packed, const int* __restrict__ Gs,
                       const float* __restrict__ dinv, const float* __restrict__ y,
                       const float* __restrict__ W1, const float* __restrict__ b1,
                       const float* __restrict__ W2,
                       float* __restrict__ gy, int E, int N, int nbkt) {
    __shared__ float acc[128];
    int b = blockIdx.x;
    if (threadIdx.x < 128) acc[threadIdx.x] = 0.f;
    __syncthreads();
    int s0 = Gs[(size_t)b * B1];
    int s1 = (b + 1 < nbkt) ? Gs[(size_t)(b + 1) * B1] : E;
    for (int i = s0 + threadIdx.x; i < s1; i += blockDim.x) {
        int p = packed[i];
        atomicAdd(&acc[p >> 20], y[p & 0xFFFFF]);
    }
    __syncthreads();
    int l = threadIdx.x;
    if (l < 128) {
        int node = (b << BKT_SHIFT) + l;
        if (node < N) {
            float di = dinv[node];
            float S = di * (acc[l] + y[node]);        // self-loop adds y[node]
            float g0 = 0.f, g1 = 0.f;
#pragma unroll
            for (int f = 0; f < 16; f++) {
                float h = fmaxf(fmaf(W1[f], S, b1[f]), 0.f);
                g0 = fmaf(h, W2[2 * f], g0);
                g1 = fmaf(h, W2[2 * f + 1], g1);
            }
            gy[2 * node]     = di * g0;               // premultiplied by dinv[src]
            gy[2 * node + 1] = di * g1;
        }
    }
}

// layer-2 aggregation (2 floats) + bias + log_softmax
__global__ void k_agg2(const int* __restrict__ packed, const int* __restrict__ Gs,
                       const float* __restrict__ dinv, const float* __restrict__ gy,
                       const float* __restrict__ b2, float* __restrict__ out,
                       int E, int N, int nbkt) {
    __shared__ float acc[256];
    int t = threadIdx.x;
    acc[t] = 0.f;   // blockDim == 256
    __syncthreads();
    int b = blockIdx.x;
    int s0 = Gs[(size_t)b * B1];
    int s1 = (b + 1 < nbkt) ? Gs[(size_t)(b + 1) * B1] : E;
    for (int i = s0 + t; i < s1; i += blockDim.x) {
        int p = packed[i];
        int l = p >> 20, s = p & 0xFFFFF;
        float2 v = ((const float2*)gy)[s];
        atomicAdd(&acc[2 * l],     v.x);
        atomicAdd(&acc[2 * l + 1], v.y);
    }
    __syncthreads();
    if (t < 128) {
        int node = (b << BKT_SHIFT) + t;
        if (node < N) {
            float di = dinv[node];
            float z0 = di * (acc[2 * t]     + gy[2 * node])     + b2[0];
            float z1 = di * (acc[2 * t + 1] + gy[2 * node + 1]) + b2[1];
            float m = fmaxf(z0, z1);
            float lse = logf(expf(z0 - m) + expf(z1 - m));
            out[2 * node]     = z0 - m - lse;
            out[2 * node + 1] = z1 - m - lse;
        }
    }
}

extern "C" void kernel_launch(void* const* d_in, const int* in_sizes, int n_in,
                              void* d_out, int out_size, void* d_ws, size_t ws_size,
                              hipStream_t stream) {
    const float* x  = (const float*)d_in[0];
    const int* ei   = (const int*)d_in[1];
    const float* W1 = (const float*)d_in[2];
    const float* b1 = (const float*)d_in[3];
    const float* W2 = (const float*)d_in[4];
    const float* b2 = (const float*)d_in[5];
    float* out = (float*)d_out;

    const int N = in_sizes[0];       // 100000
    const int E = in_sizes[1] / 2;   // 6400000
    const int* src = ei;
    const int* dst = ei + E;

    const int nbkt  = (N + BKT_MASK) >> BKT_SHIFT;       // 782
    const int chunk = (E + B1 - 1) / B1;                 // 25000 (exact)
    const int NG    = nbkt * B1;                         // 200192
    const int scanB = (NG + SCAN_T - 1) / SCAN_T;        // 391
    const int nodesPad = nbkt << BKT_SHIFT;              // 100096

    // ws layout: G[NG] | part[scanB] | packed[E] | dinv[np] | y[np] | gy[2np]
    int* G      = (int*)d_ws;
    int* part   = G + NG;
    int* packed = part + scanB;
    float* dinv = (float*)(packed + E);
    float* y    = dinv + nodesPad;
    float* gy   = y + nodesPad;

    const int BT = 256;
    const size_t ldsHist = (size_t)nbkt * sizeof(int);

    k_hist <<<B1,    BT,     ldsHist, stream>>>(dst, G, E, chunk, nbkt);
    k_scan1<<<scanB, SCAN_T, 0,       stream>>>(G, part, NG);
    k_scan2<<<1,     SCAN_T, 0,       stream>>>(part, scanB);
    k_scan3<<<scanB, SCAN_T, 0,       stream>>>(G, part, NG);
    k_place<<<B1,    BT,     ldsHist, stream>>>(src, dst, G, packed, E, chunk, nbkt);
    k_dinv_y<<<nbkt, BT,     0,       stream>>>(packed, G, x, dinv, y, E, N, nbkt);
    k_agg1 <<<nbkt,  BT,     0,       stream>>>(packed, G, dinv, y, W1, b1, W2, gy, E, N, nbkt);
    k_agg2 <<<nbkt,  BT,     0,       stream>>>(packed, G, dinv, gy, b2, out, E, N, nbkt);
}